// Round 3
// baseline (83.250 us; speedup 1.0000x reference)
//
#include <hip/hip_runtime.h>
#include <math.h>

// ---- constants from the reference ----
#define ALPHA_F   0.02f
#define BETA_F    0.015f
#define E_EX_F    0.1f
#define ZEEMAN_F  (5.79e-05f * 2.0f * 0.1f)
#define SCALE_F   ((float)(1e-11 / 6.582e-16))   // T_EVO/HBAR ~= 15193.56
#define DEPH_F    1e-4f                          // DEPH*T_EVO = 1e7*1e-11

// One fused kernel: physics + block partials + last-block final reduction.
// 4 elements per thread -> all global stores are full float4.
__global__ __launch_bounds__(256) void fused_k(
    const float* __restrict__ inp,   // (B,16)
    const float* __restrict__ sre,   // (B,2)
    const float* __restrict__ sim,   // (B,2)
    const float* __restrict__ exf,   // (Dex,3)
    const float* __restrict__ gap,   // (1,)
    float* __restrict__ out, long long out_size,
    unsigned* __restrict__ cnt,
    double* __restrict__ blkB, double* __restrict__ blkD,
    float2* __restrict__ firstS, float2* __restrict__ lastS,
    long long B, int Dex)
{
    const int t = threadIdx.x;
    const int nblk = gridDim.x;
    const long long gid = (long long)blockIdx.x * 256 + t;
    const long long e0 = gid * 4;

    // uniform constants (scalarized s_loads, L2-cached)
    float j0 = 0.f, j1 = 0.f, j2 = 0.f;
    for (int d = 0; d < Dex; ++d) { j0 += exf[d*3]; j1 += exf[d*3+1]; j2 += exf[d*3+2]; }
    const float invD = 1.f / (float)Dex;
    const float cx  = E_EX_F * (j0 * invD);
    const float cy  = E_EX_F * (j1 * invD);
    const float hzc = E_EX_F * (j2 * invD) + ZEEMAN_F + gap[0];
    const float Ef  = expf(-SCALE_F * DEPH_F);     // exp(damp)

    // ---- loads (issued up-front for ILP) ----
    float2 kk[4];
    #pragma unroll
    for (int j = 0; j < 4; ++j)
        kk[j] = *reinterpret_cast<const float2*>(inp + (e0 + j) * 16);
    const float4 reA = *reinterpret_cast<const float4*>(sre + e0 * 2);
    const float4 reB = *reinterpret_cast<const float4*>(sre + e0 * 2 + 4);
    const float4 imA = *reinterpret_cast<const float4*>(sim + e0 * 2);
    const float4 imB = *reinterpret_cast<const float4*>(sim + e0 * 2 + 4);

    const float re0[4] = {reA.x, reA.z, reB.x, reB.z};
    const float re1[4] = {reA.y, reA.w, reB.y, reB.w};
    const float im0[4] = {imA.x, imA.z, imB.x, imB.z};
    const float im1[4] = {imA.y, imA.w, imB.y, imB.w};

    const long long psi_off = 3 * B;
    const long long mom_off = 7 * B;

    float sb[12];            // packed sx,sy,sz for 4 elements
    float zx[4], zy[4];      // (sx,sy) per element for winding diffs
    double v1 = 0.0, v2 = 0.0;

    #pragma unroll
    for (int j = 0; j < 4; ++j) {
        // normalize spinor
        const float nrm = re0[j]*re0[j] + re1[j]*re1[j] + im0[j]*im0[j] + im1[j]*im1[j];
        const float inv = rsqrtf(nrm);
        const float a0r = re0[j]*inv, a0i = im0[j]*inv;
        const float a1r = re1[j]*inv, a1i = im1[j]*inv;

        // effective field
        const float hx = ALPHA_F*kk[j].y + BETA_F*kk[j].x + cx;
        const float hy = -ALPHA_F*kk[j].x - BETA_F*kk[j].y + cy;

        // closed-form U = exp(damp)*[cos th - i sin th (h.sigma)/|h|]
        const float r = sqrtf(hx*hx + hy*hy + hzc*hzc);
        float s, c;
        __sincosf(SCALE_F * r, &s, &c);
        const float f  = Ef * s / fmaxf(r, 1e-37f);
        const float Ec = Ef * c;
        const float fz = f*hzc, fx = f*hx, fy = f*hy;

        const float p0r = Ec*a0r + fz*a0i - fy*a1r + fx*a1i;
        const float p0i = Ec*a0i - fz*a0r - fy*a1i - fx*a1r;
        const float p1r = Ec*a1r - fz*a1i + fy*a0r + fx*a0i;
        const float p1i = Ec*a1i + fz*a1r + fy*a0i - fx*a0r;

        // observables
        const float crr = p0r*p1r + p0i*p1i;     // Re(p0*conj(p1))
        const float cri = p0i*p1r - p0r*p1i;     // Im(p0*conj(p1))
        const float sx = 2.f*crr, sy = 2.f*cri;
        const float sz = (p0r*p0r + p0i*p0i) - (p1r*p1r + p1i*p1i);

        sb[j*3+0] = sx; sb[j*3+1] = sy; sb[j*3+2] = sz;
        zx[j] = sx; zy[j] = sy;

        const long long o4 = psi_off + (e0 + j) * 4;
        if (o4 + 3 < out_size)
            *reinterpret_cast<float4*>(out + o4) = make_float4(p0r, p0i, p1r, p1i);

        v1 += (double)(atan2f(p1i, p1r) - atan2f(p0i, p0r));
    }

    // out_s: 12 contiguous floats (16B-aligned: 48B * gid)
    const long long os = gid * 12;
    if (os + 11 < out_size) {
        *reinterpret_cast<float4*>(out + os)     = make_float4(sb[0], sb[1], sb[2],  sb[3]);
        *reinterpret_cast<float4*>(out + os + 4) = make_float4(sb[4], sb[5], sb[6],  sb[7]);
        *reinterpret_cast<float4*>(out + os + 8) = make_float4(sb[8], sb[9], sb[10], sb[11]);
    }
    // momentum: 8 contiguous floats
    const long long om = mom_off + gid * 8;
    if (om + 7 < out_size) {
        *reinterpret_cast<float4*>(out + om)     = make_float4(kk[0].x, kk[0].y, kk[1].x, kk[1].y);
        *reinterpret_cast<float4*>(out + om + 4) = make_float4(kk[2].x, kk[2].y, kk[3].x, kk[3].y);
    }

    // winding diffs: wrap_pi(ang[i+1]-ang[i]) == atan2(cross, dot)
    #pragma unroll
    for (int j = 0; j < 3; ++j) {
        const float dot = zx[j+1]*zx[j] + zy[j+1]*zy[j];
        const float crs = zy[j+1]*zx[j] - zx[j+1]*zy[j];
        v2 += (double)atan2f(crs, dot);
    }

    __shared__ float2 sF[256];
    sF[t] = make_float2(zx[0], zy[0]);
    __syncthreads();
    if (t < 255) {
        const float2 nz = sF[t + 1];
        const float dot = nz.x*zx[3] + nz.y*zy[3];
        const float crs = nz.y*zx[3] - nz.x*zy[3];
        v2 += (double)atan2f(crs, dot);
    }
    if (t == 0)   firstS[blockIdx.x] = make_float2(zx[0], zy[0]);
    if (t == 255) lastS[blockIdx.x]  = make_float2(zx[3], zy[3]);

    // deterministic block tree reduction of (v1,v2)
    for (int o = 32; o; o >>= 1) { v1 += __shfl_down(v1, o); v2 += __shfl_down(v2, o); }
    __shared__ double rr1[4], rr2[4];
    __shared__ int sLast;
    const int wid = t >> 6, lane = t & 63;
    if (lane == 0) { rr1[wid] = v1; rr2[wid] = v2; }
    __syncthreads();
    if (t == 0) {
        blkB[blockIdx.x] = rr1[0] + rr1[1] + rr1[2] + rr1[3];
        blkD[blockIdx.x] = rr2[0] + rr2[1] + rr2[2] + rr2[3];
        __threadfence();                       // release partials (device scope)
        const unsigned tk = atomicAdd(cnt, 1u);
        sLast = (tk == (unsigned)(nblk - 1));
    }
    __syncthreads();
    if (!sLast) return;
    __threadfence();                           // acquire all blocks' partials

    // ---- last block: final reduction (fixed-order tree, deterministic) ----
    double s1 = 0.0, s2 = 0.0;
    for (int b = t; b < nblk; b += 256) { s1 += blkB[b]; s2 += blkD[b]; }
    for (int b = t; b < nblk - 1; b += 256) {
        const float2 a = lastS[b], f2 = firstS[b + 1];
        const float dot = f2.x*a.x + f2.y*a.y;
        const float crs = f2.y*a.x - f2.x*a.y;
        s2 += (double)atan2f(crs, dot);
    }
    for (int o = 32; o; o >>= 1) { s1 += __shfl_down(s1, o); s2 += __shfl_down(s2, o); }
    if (lane == 0) { rr1[wid] = s1; rr2[wid] = s2; }
    __syncthreads();
    if (t == 0 && out_size >= 2) {
        const double sum_dph  = rr1[0] + rr1[1] + rr1[2] + rr1[3];
        const double sum_dang = rr2[0] + rr2[1] + rr2[2] + rr2[3];
        double bp = sum_dph / (double)B;
        double w = fmod(bp + (double)M_PI, 2.0 * (double)M_PI);
        if (w < 0.0) w += 2.0 * (double)M_PI;
        out[out_size - 2] = (float)(w - (double)M_PI);                          // berry_phase
        out[out_size - 1] = (float)nearbyint(sum_dang / (2.0 * (double)M_PI)); // charge
    }
}

extern "C" void kernel_launch(void* const* d_in, const int* in_sizes, int n_in,
                              void* d_out, int out_size, void* d_ws, size_t ws_size,
                              hipStream_t stream) {
    (void)n_in; (void)ws_size;
    const float* inp = (const float*)d_in[0];
    const float* sre = (const float*)d_in[1];
    const float* sim = (const float*)d_in[2];
    const float* exf = (const float*)d_in[3];
    const float* gap = (const float*)d_in[4];

    const long long B   = (long long)in_sizes[0] / 16;   // 1048576
    const int       Dex = in_sizes[3] / 3;               // 16
    const int nblk = (int)(B / (256 * 4));               // 1024 blocks, 4 elem/thread

    // ws layout: [0,4) counter | 64.. blkB | blkD | firstS | lastS  (~33 KB, ws proven >= 98 KB)
    char* ws = (char*)d_ws;
    unsigned* cnt   = (unsigned*)ws;
    double*  blkB   = (double*)(ws + 64);
    double*  blkD   = (double*)(ws + 64 + (size_t)nblk * 8);
    float2*  firstS = (float2*)(ws + 64 + (size_t)nblk * 16);
    float2*  lastS  = (float2*)(ws + 64 + (size_t)nblk * 24);

    hipMemsetAsync(cnt, 0, 4, stream);   // graph-capturable memset node
    fused_k<<<nblk, 256, 0, stream>>>(inp, sre, sim, exf, gap,
                                      (float*)d_out, (long long)out_size,
                                      cnt, blkB, blkD, firstS, lastS, B, Dex);
}